// Round 1
// baseline (1859.179 us; speedup 1.0000x reference)
//
#include <hip/hip_runtime.h>
#include <math.h>

// GraphSAGE (mean) + GCN + softmax, f32.
// N=100000, E=625000, D_IN=D_H=128, D_OUT=64 (sizes derived from in_sizes).

#define DIN 128
#define DH  128
#define DOUT 64

// ---------------- edge-index dtype detection (int64 vs int32) --------------
// If data is little-endian int64 with values < 2^31, every odd int32 word is 0.
__global__ void detect_idx_kernel(const void* ei, int twoE, int* flag) {
    __shared__ int ok;
    if (threadIdx.x == 0) ok = 1;
    __syncthreads();
    const int* p = (const int*)ei;
    for (int i = threadIdx.x; i < 512; i += blockDim.x) {
        long long pos = 1 + ((long long)i * (long long)(twoE - 2)) / 512;
        pos |= 1;  // odd position
        if (pos < twoE && p[pos] != 0) ok = 0;
    }
    __syncthreads();
    if (threadIdx.x == 0) *flag = ok;  // 1 => int64, 0 => int32
}

__device__ __forceinline__ void load_edge(const void* ei, int e, int E, int is64,
                                          int& s, int& d) {
    if (is64) {
        const long long* p = (const long long*)ei;
        s = (int)p[e];
        d = (int)p[E + e];
    } else {
        const int* p = (const int*)ei;
        s = p[e];
        d = p[E + e];
    }
}

// ---------------- weight transposes --------------------------------------
// WcatT[k][o], k<128 -> W_l[o][k]; k>=128 -> W_r[o][k-128].  (256 x 128)
// WgT[k][o] = W_gcn[o][k].                                   (128 x 64)
__global__ void prep_weights(const float* __restrict__ Wl,
                             const float* __restrict__ Wr,
                             const float* __restrict__ Wg,
                             float* __restrict__ WcatT,
                             float* __restrict__ WgT) {
    int idx = blockIdx.x * blockDim.x + threadIdx.x;
    if (idx < 256 * 128) {
        int k = idx >> 7, o = idx & 127;
        WcatT[idx] = (k < 128) ? Wl[o * 128 + k] : Wr[o * 128 + (k - 128)];
    }
    int idx2 = idx - 256 * 128;
    if (idx2 >= 0 && idx2 < 128 * 64) {
        int k = idx2 >> 6, o = idx2 & 63;
        WgT[idx2] = Wg[o * 128 + k];
    }
}

// ---------------- stage 1 scatter: agg[dst] += x[src], deg[dst] += 1 -------
__global__ void scatter_agg(const void* __restrict__ ei, const int* __restrict__ flag,
                            const float* __restrict__ x,
                            float* __restrict__ agg, float* __restrict__ deg, int E) {
    int tid = blockIdx.x * 256 + threadIdx.x;
    int e = tid >> 5;
    if (e >= E) return;
    int j = tid & 31;
    int s, d;
    load_edge(ei, e, E, *flag, s, d);
    float4 xv = ((const float4*)(x + (size_t)s * DIN))[j];
    float* ap = agg + (size_t)d * DIN + j * 4;
    atomicAdd(ap + 0, xv.x);
    atomicAdd(ap + 1, xv.y);
    atomicAdd(ap + 2, xv.z);
    atomicAdd(ap + 3, xv.w);
    if (j == 0) atomicAdd(deg + d, 1.0f);
}

// ---------------- dinv = rsqrt(deg + 1) ------------------------------------
__global__ void compute_dinv(const float* __restrict__ deg, float* __restrict__ dinv, int N) {
    int i = blockIdx.x * 256 + threadIdx.x;
    if (i < N) dinv[i] = rsqrtf(deg[i] + 1.0f);
}

// ---------------- h = relu([mean|x] @ WcatT + b_l), h overwrites agg -------
// 32 nodes per block, 256 threads, 4x4 micro-tile per thread.
__global__ __launch_bounds__(256, 2) void compute_h(
    float* __restrict__ aggh,       // in: agg, out: h (same buffer, own rows only)
    const float* __restrict__ deg, const float* __restrict__ x,
    const float* __restrict__ WcatT, const float* __restrict__ bl, int N) {
    __shared__ float u[32 * 256];   // 32 KB: per-node [mean(128) | x(128)]
    __shared__ float wt[64 * 128];  // 32 KB: k-chunk of WcatT
    const int tid = threadIdx.x;
    const int n0 = blockIdx.x * 32;

    for (int idx = tid; idx < 32 * 64; idx += 256) {
        int n = idx >> 6;
        int kk = (idx & 63) << 2;
        int node = n0 + n;
        float4 v;
        if (kk < 128) {
            v = *(const float4*)(aggh + (size_t)node * DIN + kk);
            float invd = 1.0f / fmaxf(deg[node], 1.0f);
            v.x *= invd; v.y *= invd; v.z *= invd; v.w *= invd;
        } else {
            v = *(const float4*)(x + (size_t)node * DIN + (kk - 128));
        }
        *(float4*)(u + n * 256 + kk) = v;
    }

    const int tn = tid >> 5;   // 0..7  -> nodes tn*4 .. tn*4+3
    const int to = tid & 31;   // 0..31 -> outs  to*4 .. to*4+3
    float acc[4][4];
#pragma unroll
    for (int m = 0; m < 4; ++m)
#pragma unroll
        for (int o = 0; o < 4; ++o) acc[m][o] = 0.f;

    for (int kc = 0; kc < 4; ++kc) {
        __syncthreads();
        for (int idx = tid; idx < 64 * 128 / 4; idx += 256)
            *(float4*)(wt + idx * 4) = *(const float4*)(WcatT + kc * 64 * 128 + idx * 4);
        __syncthreads();
#pragma unroll 2
        for (int k = 0; k < 64; k += 4) {
            float4 wv[4];
#pragma unroll
            for (int j = 0; j < 4; ++j)
                wv[j] = *(const float4*)(wt + (k + j) * 128 + to * 4);
#pragma unroll
            for (int m = 0; m < 4; ++m) {
                float4 uv = *(const float4*)(u + (tn * 4 + m) * 256 + kc * 64 + k);
                acc[m][0] += uv.x * wv[0].x + uv.y * wv[1].x + uv.z * wv[2].x + uv.w * wv[3].x;
                acc[m][1] += uv.x * wv[0].y + uv.y * wv[1].y + uv.z * wv[2].y + uv.w * wv[3].y;
                acc[m][2] += uv.x * wv[0].z + uv.y * wv[1].z + uv.z * wv[2].z + uv.w * wv[3].z;
                acc[m][3] += uv.x * wv[0].w + uv.y * wv[1].w + uv.z * wv[2].w + uv.w * wv[3].w;
            }
        }
    }

#pragma unroll
    for (int m = 0; m < 4; ++m) {
        int node = n0 + tn * 4 + m;
        float4 hv;
        hv.x = fmaxf(acc[m][0] + bl[to * 4 + 0], 0.f);
        hv.y = fmaxf(acc[m][1] + bl[to * 4 + 1], 0.f);
        hv.z = fmaxf(acc[m][2] + bl[to * 4 + 2], 0.f);
        hv.w = fmaxf(acc[m][3] + bl[to * 4 + 3], 0.f);
        *(float4*)(aggh + (size_t)node * DH + to * 4) = hv;
    }
}

// ---------------- hw = h @ WgT  (N x 64) -----------------------------------
__global__ __launch_bounds__(256, 2) void compute_hw(
    const float* __restrict__ h, const float* __restrict__ WgT,
    float* __restrict__ hw, int N) {
    __shared__ float u[32 * 128];   // 16 KB
    __shared__ float wt[128 * 64];  // 32 KB
    const int tid = threadIdx.x;
    const int n0 = blockIdx.x * 32;

    for (int idx = tid; idx < 32 * 32; idx += 256) {
        int n = idx >> 5;
        int kk = (idx & 31) << 2;
        *(float4*)(u + n * 128 + kk) = *(const float4*)(h + (size_t)(n0 + n) * DH + kk);
    }
    for (int idx = tid; idx < 128 * 64 / 4; idx += 256)
        *(float4*)(wt + idx * 4) = *(const float4*)(WgT + idx * 4);
    __syncthreads();

    const int tn = tid >> 5;   // 4 nodes
    const int to = tid & 31;   // 2 outs
    float acc[4][2];
#pragma unroll
    for (int m = 0; m < 4; ++m) { acc[m][0] = 0.f; acc[m][1] = 0.f; }

#pragma unroll 2
    for (int k = 0; k < 128; k += 4) {
        float2 wv[4];
#pragma unroll
        for (int j = 0; j < 4; ++j)
            wv[j] = *(const float2*)(wt + (k + j) * 64 + to * 2);
#pragma unroll
        for (int m = 0; m < 4; ++m) {
            float4 uv = *(const float4*)(u + (tn * 4 + m) * 128 + k);
            acc[m][0] += uv.x * wv[0].x + uv.y * wv[1].x + uv.z * wv[2].x + uv.w * wv[3].x;
            acc[m][1] += uv.x * wv[0].y + uv.y * wv[1].y + uv.z * wv[2].y + uv.w * wv[3].y;
        }
    }

#pragma unroll
    for (int m = 0; m < 4; ++m) {
        int node = n0 + tn * 4 + m;
        float2 o;
        o.x = acc[m][0];
        o.y = acc[m][1];
        *(float2*)(hw + (size_t)node * DOUT + to * 2) = o;
    }
}

// ---------------- stage 2 scatter: out[dst] += dinv[s]*dinv[d]*hw[src] -----
__global__ void scatter_gcn(const void* __restrict__ ei, const int* __restrict__ flag,
                            const float* __restrict__ hw, const float* __restrict__ dinv,
                            float* __restrict__ outacc, int E) {
    int tid = blockIdx.x * 256 + threadIdx.x;
    int e = tid >> 4;
    if (e >= E) return;
    int j = tid & 15;
    int s, d;
    load_edge(ei, e, E, *flag, s, d);
    float nv = dinv[s] * dinv[d];
    float4 hv = ((const float4*)(hw + (size_t)s * DOUT))[j];
    float* op = outacc + (size_t)d * DOUT + j * 4;
    atomicAdd(op + 0, nv * hv.x);
    atomicAdd(op + 1, nv * hv.y);
    atomicAdd(op + 2, nv * hv.z);
    atomicAdd(op + 3, nv * hv.w);
}

// ---------------- finalize: + self-loop + bias, then row softmax -----------
// out first half holds scatter acc; second half holds hw; overwrite both.
__global__ void finalize_softmax(float* __restrict__ out, const float* __restrict__ dinv,
                                 const float* __restrict__ bg, int N) {
    int node = blockIdx.x * 4 + (threadIdx.x >> 6);
    int lane = threadIdx.x & 63;
    if (node >= N) return;
    float* hw = out + (size_t)N * DOUT;
    float di = dinv[node];
    size_t idx = (size_t)node * DOUT + lane;
    float v = out[idx] + di * di * hw[idx] + bg[lane];
    float mx = v;
#pragma unroll
    for (int off = 32; off; off >>= 1) mx = fmaxf(mx, __shfl_xor(mx, off, 64));
    float ex = __expf(v - mx);
    float sm = ex;
#pragma unroll
    for (int off = 32; off; off >>= 1) sm += __shfl_xor(sm, off, 64);
    out[idx] = v;
    hw[idx] = ex / sm;
}

// ---------------------------------------------------------------------------
extern "C" void kernel_launch(void* const* d_in, const int* in_sizes, int n_in,
                              void* d_out, int out_size, void* d_ws, size_t ws_size,
                              hipStream_t stream) {
    const float* x  = (const float*)d_in[0];
    const void*  ei = d_in[1];
    const float* Wl = (const float*)d_in[2];
    const float* bl = (const float*)d_in[3];
    const float* Wr = (const float*)d_in[4];
    const float* Wg = (const float*)d_in[5];
    const float* bg = (const float*)d_in[6];
    const int N = in_sizes[0] / DIN;
    const int E = in_sizes[1] / 2;
    float* out = (float*)d_out;

    char* ws = (char*)d_ws;
    size_t off = 0;
    int* flag = (int*)(ws + off);      off += 256;
    float* deg = (float*)(ws + off);   off += (((size_t)N * 4) + 255) / 256 * 256;
    float* dinv = (float*)(ws + off);  off += (((size_t)N * 4) + 255) / 256 * 256;
    float* WcatT = (float*)(ws + off); off += 256 * 128 * 4;
    float* WgT = (float*)(ws + off);   off += 128 * 64 * 4;
    float* aggh = (float*)(ws + off);  off += (size_t)N * DIN * 4;
    (void)ws_size; (void)n_in; (void)out_size;

    float* hw = out + (size_t)N * DOUT;   // second half of d_out doubles as hw buffer

    hipMemsetAsync(deg, 0, (size_t)N * 4, stream);
    hipMemsetAsync(aggh, 0, (size_t)N * DIN * 4, stream);
    hipMemsetAsync(out, 0, (size_t)N * DOUT * 4, stream);

    detect_idx_kernel<<<1, 256, 0, stream>>>(ei, 2 * E, flag);
    prep_weights<<<(256 * 128 + 128 * 64 + 255) / 256, 256, 0, stream>>>(Wl, Wr, Wg, WcatT, WgT);
    scatter_agg<<<(int)(((long long)E * 32 + 255) / 256), 256, 0, stream>>>(ei, flag, x, aggh, deg, E);
    compute_dinv<<<(N + 255) / 256, 256, 0, stream>>>(deg, dinv, N);
    compute_h<<<(N + 31) / 32, 256, 0, stream>>>(aggh, deg, x, WcatT, bl, N);
    compute_hw<<<(N + 31) / 32, 256, 0, stream>>>(aggh, WgT, hw, N);
    scatter_gcn<<<(int)(((long long)E * 16 + 255) / 256), 256, 0, stream>>>(ei, flag, hw, dinv, out, E);
    finalize_softmax<<<(N + 3) / 4, 256, 0, stream>>>(out, dinv, bg, N);
}

// Round 2
// 379.519 us; speedup vs baseline: 4.8988x; 4.8988x over previous
//
#include <hip/hip_runtime.h>
#include <math.h>

// GraphSAGE (mean) + GCN + softmax, f32, CSR gather formulation (no f32 atomics).
// N=100000, E=625000, D_IN=D_H=128, D_OUT=64 (derived from in_sizes).

#define DIN 128
#define DH  128
#define DOUT 64

// ---------------- edge-index dtype detection (int64 vs int32) --------------
__global__ void detect_idx_kernel(const void* ei, int twoE, int* flag) {
    __shared__ int ok;
    if (threadIdx.x == 0) ok = 1;
    __syncthreads();
    const int* p = (const int*)ei;
    for (int i = threadIdx.x; i < 512; i += blockDim.x) {
        long long pos = 1 + ((long long)i * (long long)(twoE - 2)) / 512;
        pos |= 1;  // odd int32 word of an int64 lane
        if (pos < twoE && p[pos] != 0) ok = 0;
    }
    __syncthreads();
    if (threadIdx.x == 0) *flag = ok;  // 1 => int64, 0 => int32
}

__device__ __forceinline__ void load_edge(const void* ei, int e, int E, int is64,
                                          int& s, int& d) {
    if (is64) {
        const long long* p = (const long long*)ei;
        s = (int)p[e];
        d = (int)p[E + e];
    } else {
        const int* p = (const int*)ei;
        s = p[e];
        d = p[E + e];
    }
}

// ---------------- weight transposes ---------------------------------------
__global__ void prep_weights(const float* __restrict__ Wl,
                             const float* __restrict__ Wr,
                             const float* __restrict__ Wg,
                             float* __restrict__ WcatT,
                             float* __restrict__ WgT) {
    int idx = blockIdx.x * blockDim.x + threadIdx.x;
    if (idx < 256 * 128) {
        int k = idx >> 7, o = idx & 127;
        WcatT[idx] = (k < 128) ? Wl[o * 128 + k] : Wr[o * 128 + (k - 128)];
    }
    int idx2 = idx - 256 * 128;
    if (idx2 >= 0 && idx2 < 128 * 64) {
        int k = idx2 >> 6, o = idx2 & 63;
        WgT[idx2] = Wg[o * 128 + k];
    }
}

// ---------------- CSR build -----------------------------------------------
__global__ void count_deg(const void* __restrict__ ei, const int* __restrict__ flag,
                          int* __restrict__ deg, int E) {
    int e = blockIdx.x * 256 + threadIdx.x;
    if (e >= E) return;
    int s, d;
    load_edge(ei, e, E, *flag, s, d);
    atomicAdd(&deg[d], 1);
}

// block handles 1024 elements -> partial[b] = sum
__global__ void scan_partial(const int* __restrict__ deg, int* __restrict__ partial, int N) {
    int base = blockIdx.x * 1024;
    int t = threadIdx.x;
    int s = 0;
    for (int i = t; i < 1024; i += 256) {
        int g = base + i;
        if (g < N) s += deg[g];
    }
    __shared__ int sh[256];
    sh[t] = s;
    __syncthreads();
    for (int off = 128; off; off >>= 1) {
        if (t < off) sh[t] += sh[t + off];
        __syncthreads();
    }
    if (t == 0) partial[blockIdx.x] = sh[0];
}

__global__ void scan_offsets(int* partial, int nblk, int* rowptr, int N, int E) {
    if (threadIdx.x == 0 && blockIdx.x == 0) {
        int run = 0;
        for (int i = 0; i < nblk; ++i) {
            int v = partial[i];
            partial[i] = run;
            run += v;
        }
        rowptr[N] = E;
    }
}

// local exclusive scan + global offset; also emits cursor copy and dinv
__global__ void scan_final(const int* __restrict__ deg, const int* __restrict__ partial,
                           int* __restrict__ rowptr, int* __restrict__ cursor,
                           float* __restrict__ dinv, int N) {
    int base = blockIdx.x * 1024;
    int t = threadIdx.x;
    int i0 = base + t * 4;
    int v[4];
    int s = 0;
#pragma unroll
    for (int j = 0; j < 4; ++j) {
        int g = i0 + j;
        v[j] = (g < N) ? deg[g] : 0;
        s += v[j];
    }
    __shared__ int sh[256];
    sh[t] = s;
    __syncthreads();
    for (int off = 1; off < 256; off <<= 1) {
        int val = (t >= off) ? sh[t - off] : 0;
        __syncthreads();
        sh[t] += val;
        __syncthreads();
    }
    int pre = sh[t] - s + partial[blockIdx.x];
#pragma unroll
    for (int j = 0; j < 4; ++j) {
        int g = i0 + j;
        if (g < N) {
            rowptr[g] = pre;
            cursor[g] = pre;
            dinv[g] = rsqrtf((float)v[j] + 1.0f);
            pre += v[j];
        }
    }
}

__global__ void fill_csr(const void* __restrict__ ei, const int* __restrict__ flag,
                         int* __restrict__ cursor, int* __restrict__ col, int E) {
    int e = blockIdx.x * 256 + threadIdx.x;
    if (e >= E) return;
    int s, d;
    load_edge(ei, e, E, *flag, s, d);
    int pos = atomicAdd(&cursor[d], 1);
    col[pos] = s;
}

// ---------------- gather mean: mean[n] = (1/max(deg,1)) * sum x[col] -------
__global__ void gather_agg(const int* __restrict__ rowptr, const int* __restrict__ col,
                           const float* __restrict__ x, float* __restrict__ mean, int N) {
    int node = blockIdx.x * 4 + (threadIdx.x >> 6);
    if (node >= N) return;
    int lane = threadIdx.x & 63;
    int beg = rowptr[node], end = rowptr[node + 1];
    float2 acc = make_float2(0.f, 0.f);
    int e = beg;
    // 2-deep manual pipeline for load latency
    for (; e + 1 < end; e += 2) {
        int s0 = col[e], s1 = col[e + 1];
        float2 v0 = *(const float2*)(x + (size_t)s0 * DIN + lane * 2);
        float2 v1 = *(const float2*)(x + (size_t)s1 * DIN + lane * 2);
        acc.x += v0.x + v1.x;
        acc.y += v0.y + v1.y;
    }
    if (e < end) {
        int s0 = col[e];
        float2 v0 = *(const float2*)(x + (size_t)s0 * DIN + lane * 2);
        acc.x += v0.x;
        acc.y += v0.y;
    }
    float invd = (end > beg) ? 1.0f / (float)(end - beg) : 0.f;
    acc.x *= invd;
    acc.y *= invd;
    *(float2*)(mean + (size_t)node * DIN + lane * 2) = acc;
}

// ---------------- h = relu([mean|x] @ WcatT + b_l), h overwrites mean ------
__global__ __launch_bounds__(256, 2) void compute_h(
    float* __restrict__ aggh,       // in: mean, out: h (same buffer, own rows only)
    const float* __restrict__ x,
    const float* __restrict__ WcatT, const float* __restrict__ bl, int N) {
    __shared__ float u[32 * 256];
    __shared__ float wt[64 * 128];
    const int tid = threadIdx.x;
    const int n0 = blockIdx.x * 32;

    for (int idx = tid; idx < 32 * 64; idx += 256) {
        int n = idx >> 6;
        int kk = (idx & 63) << 2;
        int node = n0 + n;
        float4 v;
        if (kk < 128) {
            v = *(const float4*)(aggh + (size_t)node * DIN + kk);
        } else {
            v = *(const float4*)(x + (size_t)node * DIN + (kk - 128));
        }
        *(float4*)(u + n * 256 + kk) = v;
    }

    const int tn = tid >> 5;
    const int to = tid & 31;
    float acc[4][4];
#pragma unroll
    for (int m = 0; m < 4; ++m)
#pragma unroll
        for (int o = 0; o < 4; ++o) acc[m][o] = 0.f;

    for (int kc = 0; kc < 4; ++kc) {
        __syncthreads();
        for (int idx = tid; idx < 64 * 128 / 4; idx += 256)
            *(float4*)(wt + idx * 4) = *(const float4*)(WcatT + kc * 64 * 128 + idx * 4);
        __syncthreads();
#pragma unroll 2
        for (int k = 0; k < 64; k += 4) {
            float4 wv[4];
#pragma unroll
            for (int j = 0; j < 4; ++j)
                wv[j] = *(const float4*)(wt + (k + j) * 128 + to * 4);
#pragma unroll
            for (int m = 0; m < 4; ++m) {
                float4 uv = *(const float4*)(u + (tn * 4 + m) * 256 + kc * 64 + k);
                acc[m][0] += uv.x * wv[0].x + uv.y * wv[1].x + uv.z * wv[2].x + uv.w * wv[3].x;
                acc[m][1] += uv.x * wv[0].y + uv.y * wv[1].y + uv.z * wv[2].y + uv.w * wv[3].y;
                acc[m][2] += uv.x * wv[0].z + uv.y * wv[1].z + uv.z * wv[2].z + uv.w * wv[3].z;
                acc[m][3] += uv.x * wv[0].w + uv.y * wv[1].w + uv.z * wv[2].w + uv.w * wv[3].w;
            }
        }
    }

#pragma unroll
    for (int m = 0; m < 4; ++m) {
        int node = n0 + tn * 4 + m;
        float4 hv;
        hv.x = fmaxf(acc[m][0] + bl[to * 4 + 0], 0.f);
        hv.y = fmaxf(acc[m][1] + bl[to * 4 + 1], 0.f);
        hv.z = fmaxf(acc[m][2] + bl[to * 4 + 2], 0.f);
        hv.w = fmaxf(acc[m][3] + bl[to * 4 + 3], 0.f);
        *(float4*)(aggh + (size_t)node * DH + to * 4) = hv;
    }
}

// ---------------- hw = h @ WgT  (N x 64) -----------------------------------
__global__ __launch_bounds__(256, 2) void compute_hw(
    const float* __restrict__ h, const float* __restrict__ WgT,
    float* __restrict__ hw, int N) {
    __shared__ float u[32 * 128];
    __shared__ float wt[128 * 64];
    const int tid = threadIdx.x;
    const int n0 = blockIdx.x * 32;

    for (int idx = tid; idx < 32 * 32; idx += 256) {
        int n = idx >> 5;
        int kk = (idx & 31) << 2;
        *(float4*)(u + n * 128 + kk) = *(const float4*)(h + (size_t)(n0 + n) * DH + kk);
    }
    for (int idx = tid; idx < 128 * 64 / 4; idx += 256)
        *(float4*)(wt + idx * 4) = *(const float4*)(WgT + idx * 4);
    __syncthreads();

    const int tn = tid >> 5;
    const int to = tid & 31;
    float acc[4][2];
#pragma unroll
    for (int m = 0; m < 4; ++m) { acc[m][0] = 0.f; acc[m][1] = 0.f; }

#pragma unroll 2
    for (int k = 0; k < 128; k += 4) {
        float2 wv[4];
#pragma unroll
        for (int j = 0; j < 4; ++j)
            wv[j] = *(const float2*)(wt + (k + j) * 64 + to * 2);
#pragma unroll
        for (int m = 0; m < 4; ++m) {
            float4 uv = *(const float4*)(u + (tn * 4 + m) * 128 + k);
            acc[m][0] += uv.x * wv[0].x + uv.y * wv[1].x + uv.z * wv[2].x + uv.w * wv[3].x;
            acc[m][1] += uv.x * wv[0].y + uv.y * wv[1].y + uv.z * wv[2].y + uv.w * wv[3].y;
        }
    }

#pragma unroll
    for (int m = 0; m < 4; ++m) {
        int node = n0 + tn * 4 + m;
        float2 o;
        o.x = acc[m][0];
        o.y = acc[m][1];
        *(float2*)(hw + (size_t)node * DOUT + to * 2) = o;
    }
}

// ---------------- gather GCN: v = di*sum(dinv[s]*hw[s]) + di^2*hw[n] + bg --
__global__ void gather_gcn(const int* __restrict__ rowptr, const int* __restrict__ col,
                           const float* __restrict__ hw, const float* __restrict__ dinv,
                           const float* __restrict__ bg, float* __restrict__ out, int N) {
    int node = blockIdx.x * 4 + (threadIdx.x >> 6);
    if (node >= N) return;
    int lane = threadIdx.x & 63;
    int beg = rowptr[node], end = rowptr[node + 1];
    float c = 0.f;
    int e = beg;
    for (; e + 1 < end; e += 2) {
        int s0 = col[e], s1 = col[e + 1];
        float w0 = dinv[s0], w1 = dinv[s1];
        float h0 = hw[(size_t)s0 * DOUT + lane];
        float h1 = hw[(size_t)s1 * DOUT + lane];
        c += w0 * h0 + w1 * h1;
    }
    if (e < end) {
        int s0 = col[e];
        c += dinv[s0] * hw[(size_t)s0 * DOUT + lane];
    }
    float di = dinv[node];
    float v = di * c + di * di * hw[(size_t)node * DOUT + lane] + bg[lane];
    out[(size_t)node * DOUT + lane] = v;
}

// ---------------- softmax over 64 cols (second half of d_out) --------------
__global__ void softmax_k(const float* __restrict__ v, float* __restrict__ soft, int N) {
    int node = blockIdx.x * 4 + (threadIdx.x >> 6);
    if (node >= N) return;
    int lane = threadIdx.x & 63;
    float val = v[(size_t)node * DOUT + lane];
    float mx = val;
#pragma unroll
    for (int off = 32; off; off >>= 1) mx = fmaxf(mx, __shfl_xor(mx, off, 64));
    float ex = __expf(val - mx);
    float sm = ex;
#pragma unroll
    for (int off = 32; off; off >>= 1) sm += __shfl_xor(sm, off, 64);
    soft[(size_t)node * DOUT + lane] = ex / sm;
}

// ---------------------------------------------------------------------------
extern "C" void kernel_launch(void* const* d_in, const int* in_sizes, int n_in,
                              void* d_out, int out_size, void* d_ws, size_t ws_size,
                              hipStream_t stream) {
    const float* x  = (const float*)d_in[0];
    const void*  ei = d_in[1];
    const float* Wl = (const float*)d_in[2];
    const float* bl = (const float*)d_in[3];
    const float* Wr = (const float*)d_in[4];
    const float* Wg = (const float*)d_in[5];
    const float* bg = (const float*)d_in[6];
    const int N = in_sizes[0] / DIN;
    const int E = in_sizes[1] / 2;
    float* out = (float*)d_out;

    char* ws = (char*)d_ws;
    size_t off = 0;
    auto alloc = [&](size_t bytes) {
        void* p = ws + off;
        off += (bytes + 255) / 256 * 256;
        return p;
    };
    int*   flag    = (int*)alloc(4);
    int*   deg     = (int*)alloc((size_t)N * 4);
    float* dinv    = (float*)alloc((size_t)N * 4);
    int*   rowptr  = (int*)alloc((size_t)(N + 1) * 4);
    int*   cursor  = (int*)alloc((size_t)N * 4);
    int*   colv    = (int*)alloc((size_t)E * 4);
    int*   partial = (int*)alloc(1024 * 4);
    float* WcatT   = (float*)alloc(256 * 128 * 4);
    float* WgT     = (float*)alloc(128 * 64 * 4);
    float* aggh    = (float*)alloc((size_t)N * DIN * 4);
    (void)ws_size; (void)n_in; (void)out_size;

    float* hw = out + (size_t)N * DOUT;   // second half of d_out doubles as hw buffer

    const int nblk = (N + 1023) / 1024;

    hipMemsetAsync(deg, 0, (size_t)N * 4, stream);

    detect_idx_kernel<<<1, 256, 0, stream>>>(ei, 2 * E, flag);
    prep_weights<<<(256 * 128 + 128 * 64 + 255) / 256, 256, 0, stream>>>(Wl, Wr, Wg, WcatT, WgT);
    count_deg<<<(E + 255) / 256, 256, 0, stream>>>(ei, flag, deg, E);
    scan_partial<<<nblk, 256, 0, stream>>>(deg, partial, N);
    scan_offsets<<<1, 64, 0, stream>>>(partial, nblk, rowptr, N, E);
    scan_final<<<nblk, 256, 0, stream>>>(deg, partial, rowptr, cursor, dinv, N);
    fill_csr<<<(E + 255) / 256, 256, 0, stream>>>(ei, flag, cursor, colv, E);
    gather_agg<<<(N + 3) / 4, 256, 0, stream>>>(rowptr, colv, x, aggh, N);
    compute_h<<<(N + 31) / 32, 256, 0, stream>>>(aggh, x, WcatT, bl, N);
    compute_hw<<<(N + 31) / 32, 256, 0, stream>>>(aggh, WgT, hw, N);
    gather_gcn<<<(N + 3) / 4, 256, 0, stream>>>(rowptr, colv, hw, dinv, bg, out, N);
    softmax_k<<<(N + 3) / 4, 256, 0, stream>>>(out, hw, N);
}

// Round 3
// 279.711 us; speedup vs baseline: 6.6468x; 1.3568x over previous
//
#include <hip/hip_runtime.h>
#include <math.h>

// GraphSAGE (mean) + GCN + softmax, f32 semantics via split-bf16 MFMA.
// N=100000, E=625000, D_IN=D_H=128, D_OUT=64 (derived from in_sizes).

#define DIN 128
#define DH  128
#define DOUT 64
#define U_STR 264   // 256 + 8 pad (ushort) -> row stride 528B, 2-way bank alias (free)
#define H_STR 136   // 128 + 8 pad (ushort) -> row stride 272B, 2-way bank alias (free)

typedef __attribute__((ext_vector_type(8))) short short8v;   // 8 bf16
typedef __attribute__((ext_vector_type(4))) float float4v;   // MFMA acc

// split f32 -> bf16 hi (truncate) + bf16 lo (residual, truncate)
__device__ __forceinline__ void splitf(float a, unsigned short& hi, unsigned short& lo) {
    unsigned ai = __float_as_uint(a);
    hi = (unsigned short)(ai >> 16);
    float r = a - __uint_as_float(ai & 0xffff0000u);
    lo = (unsigned short)(__float_as_uint(r) >> 16);
}

// ---------------- edge-index dtype detection (int64 vs int32) --------------
__global__ void detect_idx_kernel(const void* ei, int twoE, int* flag) {
    __shared__ int ok;
    if (threadIdx.x == 0) ok = 1;
    __syncthreads();
    const int* p = (const int*)ei;
    for (int i = threadIdx.x; i < 512; i += blockDim.x) {
        long long pos = 1 + ((long long)i * (long long)(twoE - 2)) / 512;
        pos |= 1;
        if (pos < twoE && p[pos] != 0) ok = 0;
    }
    __syncthreads();
    if (threadIdx.x == 0) *flag = ok;  // 1 => int64, 0 => int32
}

__device__ __forceinline__ void load_edge(const void* ei, int e, int E, int is64,
                                          int& s, int& d) {
    if (is64) {
        const long long* p = (const long long*)ei;
        s = (int)p[e];
        d = (int)p[E + e];
    } else {
        const int* p = (const int*)ei;
        s = p[e];
        d = p[E + e];
    }
}

// ---------------- weight split to bf16 hi/lo (no transpose needed) ---------
// Wcat[o][k]: o<128 outs; k<128 -> W_l[o][k], k>=128 -> W_r[o][k-128]
// Wg[o][k] = W_gcn (already row-major [o][k])
__global__ void prep_weights_split(const float* __restrict__ Wl, const float* __restrict__ Wr,
                                   const float* __restrict__ Wg,
                                   unsigned short* __restrict__ WcH, unsigned short* __restrict__ WcL,
                                   unsigned short* __restrict__ WgH, unsigned short* __restrict__ WgL) {
    int idx = blockIdx.x * 256 + threadIdx.x;
    if (idx < 128 * 256) {
        int o = idx >> 8, k = idx & 255;
        float v = (k < 128) ? Wl[o * 128 + k] : Wr[o * 128 + (k - 128)];
        splitf(v, WcH[idx], WcL[idx]);
    } else {
        int j = idx - 128 * 256;
        if (j < 64 * 128) splitf(Wg[j], WgH[j], WgL[j]);
    }
}

// ---------------- CSR build -----------------------------------------------
__global__ void count_deg(const void* __restrict__ ei, const int* __restrict__ flag,
                          int* __restrict__ deg, int E) {
    int e = blockIdx.x * 256 + threadIdx.x;
    if (e >= E) return;
    int s, d;
    load_edge(ei, e, E, *flag, s, d);
    atomicAdd(&deg[d], 1);
}

__global__ void scan_partial(const int* __restrict__ deg, int* __restrict__ partial, int N) {
    int base = blockIdx.x * 1024;
    int t = threadIdx.x;
    int s = 0;
    for (int i = t; i < 1024; i += 256) {
        int g = base + i;
        if (g < N) s += deg[g];
    }
    __shared__ int sh[256];
    sh[t] = s;
    __syncthreads();
    for (int off = 128; off; off >>= 1) {
        if (t < off) sh[t] += sh[t + off];
        __syncthreads();
    }
    if (t == 0) partial[blockIdx.x] = sh[0];
}

__global__ void scan_offsets(int* partial, int nblk, int* rowptr, int N, int E) {
    if (threadIdx.x == 0 && blockIdx.x == 0) {
        int run = 0;
        for (int i = 0; i < nblk; ++i) {
            int v = partial[i];
            partial[i] = run;
            run += v;
        }
        rowptr[N] = E;
    }
}

__global__ void scan_final(const int* __restrict__ deg, const int* __restrict__ partial,
                           int* __restrict__ rowptr, int* __restrict__ cursor,
                           float* __restrict__ dinv, int N) {
    int base = blockIdx.x * 1024;
    int t = threadIdx.x;
    int i0 = base + t * 4;
    int v[4];
    int s = 0;
#pragma unroll
    for (int j = 0; j < 4; ++j) {
        int g = i0 + j;
        v[j] = (g < N) ? deg[g] : 0;
        s += v[j];
    }
    __shared__ int sh[256];
    sh[t] = s;
    __syncthreads();
    for (int off = 1; off < 256; off <<= 1) {
        int val = (t >= off) ? sh[t - off] : 0;
        __syncthreads();
        sh[t] += val;
        __syncthreads();
    }
    int pre = sh[t] - s + partial[blockIdx.x];
#pragma unroll
    for (int j = 0; j < 4; ++j) {
        int g = i0 + j;
        if (g < N) {
            rowptr[g] = pre;
            cursor[g] = pre;
            dinv[g] = rsqrtf((float)v[j] + 1.0f);
            pre += v[j];
        }
    }
}

__global__ void fill_csr(const void* __restrict__ ei, const int* __restrict__ flag,
                         int* __restrict__ cursor, int* __restrict__ col, int E) {
    int e = blockIdx.x * 256 + threadIdx.x;
    if (e >= E) return;
    int s, d;
    load_edge(ei, e, E, *flag, s, d);
    int pos = atomicAdd(&cursor[d], 1);
    col[pos] = s;
}

// ---------------- gather mean (one wave per node) --------------------------
__global__ void gather_agg(const int* __restrict__ rowptr, const int* __restrict__ col,
                           const float* __restrict__ x, float* __restrict__ mean, int N) {
    int node = blockIdx.x * 4 + (threadIdx.x >> 6);
    if (node >= N) return;
    int lane = threadIdx.x & 63;
    int beg = rowptr[node], end = rowptr[node + 1];
    float2 acc = make_float2(0.f, 0.f);
    int e = beg;
    for (; e + 1 < end; e += 2) {
        int s0 = col[e], s1 = col[e + 1];
        float2 v0 = *(const float2*)(x + (size_t)s0 * DIN + lane * 2);
        float2 v1 = *(const float2*)(x + (size_t)s1 * DIN + lane * 2);
        acc.x += v0.x + v1.x;
        acc.y += v0.y + v1.y;
    }
    if (e < end) {
        int s0 = col[e];
        float2 v0 = *(const float2*)(x + (size_t)s0 * DIN + lane * 2);
        acc.x += v0.x;
        acc.y += v0.y;
    }
    float invd = (end > beg) ? 1.0f / (float)(end - beg) : 0.f;
    acc.x *= invd;
    acc.y *= invd;
    *(float2*)(mean + (size_t)node * DH + lane * 2) = acc;
}

// ---------------- fused: h = relu([mean|x]@Wcat^T + bl); hw = h@Wg^T -------
// 32 nodes/block, 256 threads (4 waves). Split-bf16, 3 MFMA per tile-pair.
// hw written strided-128 into the SAME buffer as mean (block overwrites only
// the rows it already consumed -> no cross-block race).
__global__ __launch_bounds__(256) void fused_h_hw(
    const float* __restrict__ mean_, const float* __restrict__ x,
    const unsigned short* __restrict__ WcH, const unsigned short* __restrict__ WcL,
    const unsigned short* __restrict__ WgH, const unsigned short* __restrict__ WgL,
    const float* __restrict__ bl, float* __restrict__ hw, int N)
{
    __shared__ unsigned short usH[32 * U_STR];
    __shared__ unsigned short usL[32 * U_STR];
    __shared__ unsigned short hsH[32 * H_STR];
    __shared__ unsigned short hsL[32 * H_STR];
    const int tid = threadIdx.x;
    const int n0 = blockIdx.x * 32;

    // ---- stage u = [mean(128) | x(128)] as bf16 hi/lo
    for (int idx = tid; idx < 32 * 64; idx += 256) {
        int n = idx >> 6;
        int kq = (idx & 63) << 2;
        int node = n0 + n;
        if (node >= N) node = N - 1;
        float4 v = (kq < 128)
                       ? *(const float4*)(mean_ + (size_t)node * DH + kq)
                       : *(const float4*)(x + (size_t)node * DIN + (kq - 128));
        int base = n * U_STR + kq;
        splitf(v.x, usH[base + 0], usL[base + 0]);
        splitf(v.y, usH[base + 1], usL[base + 1]);
        splitf(v.z, usH[base + 2], usL[base + 2]);
        splitf(v.w, usH[base + 3], usL[base + 3]);
    }
    __syncthreads();

    const int wave = tid >> 6;
    const int lane = tid & 63;
    const int lrow = lane & 15;        // A-row / B-col(out) / D-col
    const int lk8  = (lane >> 4) << 3; // k base within K=32 step
    const int qr   = (lane >> 4) << 2; // D-row base

    // ---- GEMM1: h[32x128] = u[32x256] @ Wcat^T, wave handles cols [wave*32, +32)
    float4v acc00 = {0.f, 0.f, 0.f, 0.f};
    float4v acc01 = {0.f, 0.f, 0.f, 0.f};
    float4v acc10 = {0.f, 0.f, 0.f, 0.f};
    float4v acc11 = {0.f, 0.f, 0.f, 0.f};
    const int o0 = wave * 32 + lrow;   // B row (out index), col-tile 0
    const int o1 = o0 + 16;            // col-tile 1

#pragma unroll
    for (int ks = 0; ks < 8; ++ks) {
        int kb = ks * 32 + lk8;
        short8v a0h = *(const short8v*)&usH[lrow * U_STR + kb];
        short8v a0l = *(const short8v*)&usL[lrow * U_STR + kb];
        short8v a1h = *(const short8v*)&usH[(16 + lrow) * U_STR + kb];
        short8v a1l = *(const short8v*)&usL[(16 + lrow) * U_STR + kb];
        short8v b0h = *(const short8v*)(WcH + o0 * 256 + kb);
        short8v b0l = *(const short8v*)(WcL + o0 * 256 + kb);
        short8v b1h = *(const short8v*)(WcH + o1 * 256 + kb);
        short8v b1l = *(const short8v*)(WcL + o1 * 256 + kb);
        acc00 = __builtin_amdgcn_mfma_f32_16x16x32_bf16(a0h, b0h, acc00, 0, 0, 0);
        acc00 = __builtin_amdgcn_mfma_f32_16x16x32_bf16(a0h, b0l, acc00, 0, 0, 0);
        acc00 = __builtin_amdgcn_mfma_f32_16x16x32_bf16(a0l, b0h, acc00, 0, 0, 0);
        acc01 = __builtin_amdgcn_mfma_f32_16x16x32_bf16(a0h, b1h, acc01, 0, 0, 0);
        acc01 = __builtin_amdgcn_mfma_f32_16x16x32_bf16(a0h, b1l, acc01, 0, 0, 0);
        acc01 = __builtin_amdgcn_mfma_f32_16x16x32_bf16(a0l, b1h, acc01, 0, 0, 0);
        acc10 = __builtin_amdgcn_mfma_f32_16x16x32_bf16(a1h, b0h, acc10, 0, 0, 0);
        acc10 = __builtin_amdgcn_mfma_f32_16x16x32_bf16(a1h, b0l, acc10, 0, 0, 0);
        acc10 = __builtin_amdgcn_mfma_f32_16x16x32_bf16(a1l, b0h, acc10, 0, 0, 0);
        acc11 = __builtin_amdgcn_mfma_f32_16x16x32_bf16(a1h, b1h, acc11, 0, 0, 0);
        acc11 = __builtin_amdgcn_mfma_f32_16x16x32_bf16(a1h, b1l, acc11, 0, 0, 0);
        acc11 = __builtin_amdgcn_mfma_f32_16x16x32_bf16(a1l, b1h, acc11, 0, 0, 0);
    }

    // ---- bias + ReLU + split h into LDS (D layout: col=lrow-of-tile, row=qr+q)
    {
        float bb0 = bl[wave * 32 + lrow];
        float bb1 = bl[wave * 32 + 16 + lrow];
        int c0 = wave * 32 + lrow;
        int c1 = c0 + 16;
#pragma unroll
        for (int q = 0; q < 4; ++q) {
            int r0 = qr + q;        // row tile 0
            int r1 = 16 + qr + q;   // row tile 1
            float v;
            v = fmaxf(acc00[q] + bb0, 0.f); splitf(v, hsH[r0 * H_STR + c0], hsL[r0 * H_STR + c0]);
            v = fmaxf(acc01[q] + bb1, 0.f); splitf(v, hsH[r0 * H_STR + c1], hsL[r0 * H_STR + c1]);
            v = fmaxf(acc10[q] + bb0, 0.f); splitf(v, hsH[r1 * H_STR + c0], hsL[r1 * H_STR + c0]);
            v = fmaxf(acc11[q] + bb1, 0.f); splitf(v, hsH[r1 * H_STR + c1], hsL[r1 * H_STR + c1]);
        }
    }
    __syncthreads();

    // ---- GEMM2: hw[32x64] = h[32x128] @ Wg^T, wave handles col-tile `wave`
    float4v acc2_0 = {0.f, 0.f, 0.f, 0.f};
    float4v acc2_1 = {0.f, 0.f, 0.f, 0.f};
    const int og = wave * 16 + lrow;
#pragma unroll
    for (int ks = 0; ks < 4; ++ks) {
        int kb = ks * 32 + lk8;
        short8v a0h = *(const short8v*)&hsH[lrow * H_STR + kb];
        short8v a0l = *(const short8v*)&hsL[lrow * H_STR + kb];
        short8v a1h = *(const short8v*)&hsH[(16 + lrow) * H_STR + kb];
        short8v a1l = *(const short8v*)&hsL[(16 + lrow) * H_STR + kb];
        short8v bh = *(const short8v*)(WgH + og * 128 + kb);
        short8v bl8 = *(const short8v*)(WgL + og * 128 + kb);
        acc2_0 = __builtin_amdgcn_mfma_f32_16x16x32_bf16(a0h, bh, acc2_0, 0, 0, 0);
        acc2_0 = __builtin_amdgcn_mfma_f32_16x16x32_bf16(a0h, bl8, acc2_0, 0, 0, 0);
        acc2_0 = __builtin_amdgcn_mfma_f32_16x16x32_bf16(a0l, bh, acc2_0, 0, 0, 0);
        acc2_1 = __builtin_amdgcn_mfma_f32_16x16x32_bf16(a1h, bh, acc2_1, 0, 0, 0);
        acc2_1 = __builtin_amdgcn_mfma_f32_16x16x32_bf16(a1h, bl8, acc2_1, 0, 0, 0);
        acc2_1 = __builtin_amdgcn_mfma_f32_16x16x32_bf16(a1l, bh, acc2_1, 0, 0, 0);
    }

    // ---- write hw strided-128 (overwrites this block's mean rows only)
#pragma unroll
    for (int q = 0; q < 4; ++q) {
        int node0 = n0 + qr + q;
        int node1 = n0 + 16 + qr + q;
        if (node0 < N) hw[(size_t)node0 * 128 + og] = acc2_0[q];
        if (node1 < N) hw[(size_t)node1 * 128 + og] = acc2_1[q];
    }
}

// ---------------- gather GCN + fused softmax (one wave per node) -----------
__global__ void gather_gcn_softmax(const int* __restrict__ rowptr, const int* __restrict__ col,
                                   const float* __restrict__ hw, const float* __restrict__ dinv,
                                   const float* __restrict__ bg,
                                   float* __restrict__ out, float* __restrict__ soft, int N) {
    int node = blockIdx.x * 4 + (threadIdx.x >> 6);
    if (node >= N) return;
    int lane = threadIdx.x & 63;
    int beg = rowptr[node], end = rowptr[node + 1];
    float c = 0.f;
    int e = beg;
    for (; e + 1 < end; e += 2) {
        int s0 = col[e], s1 = col[e + 1];
        float w0 = dinv[s0], w1 = dinv[s1];
        float h0 = hw[(size_t)s0 * 128 + lane];
        float h1 = hw[(size_t)s1 * 128 + lane];
        c += w0 * h0 + w1 * h1;
    }
    if (e < end) {
        int s0 = col[e];
        c += dinv[s0] * hw[(size_t)s0 * 128 + lane];
    }
    float di = dinv[node];
    float v = di * c + di * di * hw[(size_t)node * 128 + lane] + bg[lane];
    float mx = v;
#pragma unroll
    for (int off = 32; off; off >>= 1) mx = fmaxf(mx, __shfl_xor(mx, off, 64));
    float ex = __expf(v - mx);
    float sm = ex;
#pragma unroll
    for (int off = 32; off; off >>= 1) sm += __shfl_xor(sm, off, 64);
    out[(size_t)node * DOUT + lane] = v;
    soft[(size_t)node * DOUT + lane] = ex / sm;
}

// ---------------------------------------------------------------------------
extern "C" void kernel_launch(void* const* d_in, const int* in_sizes, int n_in,
                              void* d_out, int out_size, void* d_ws, size_t ws_size,
                              hipStream_t stream) {
    const float* x  = (const float*)d_in[0];
    const void*  ei = d_in[1];
    const float* Wl = (const float*)d_in[2];
    const float* bl = (const float*)d_in[3];
    const float* Wr = (const float*)d_in[4];
    const float* Wg = (const float*)d_in[5];
    const float* bg = (const float*)d_in[6];
    const int N = in_sizes[0] / DIN;
    const int E = in_sizes[1] / 2;
    float* out = (float*)d_out;

    char* ws = (char*)d_ws;
    size_t off = 0;
    auto alloc = [&](size_t bytes) {
        void* p = ws + off;
        off += (bytes + 255) / 256 * 256;
        return p;
    };
    int*   flag    = (int*)alloc(4);
    int*   deg     = (int*)alloc((size_t)N * 4);
    float* dinv    = (float*)alloc((size_t)N * 4);
    int*   rowptr  = (int*)alloc((size_t)(N + 1) * 4);
    int*   cursor  = (int*)alloc((size_t)N * 4);
    int*   colv    = (int*)alloc((size_t)E * 4);
    int*   partial = (int*)alloc(1024 * 4);
    unsigned short* WcH = (unsigned short*)alloc(128 * 256 * 2);
    unsigned short* WcL = (unsigned short*)alloc(128 * 256 * 2);
    unsigned short* WgH = (unsigned short*)alloc(64 * 128 * 2);
    unsigned short* WgL = (unsigned short*)alloc(64 * 128 * 2);
    float* aggh    = (float*)alloc((size_t)N * DH * 4);   // mean, then hw (strided 128)
    (void)ws_size; (void)n_in; (void)out_size;

    float* soft = out + (size_t)N * DOUT;   // second half of d_out = softmax

    const int nblk = (N + 1023) / 1024;

    hipMemsetAsync(deg, 0, (size_t)N * 4, stream);

    detect_idx_kernel<<<1, 256, 0, stream>>>(ei, 2 * E, flag);
    prep_weights_split<<<160, 256, 0, stream>>>(Wl, Wr, Wg, WcH, WcL, WgH, WgL);
    count_deg<<<(E + 255) / 256, 256, 0, stream>>>(ei, flag, deg, E);
    scan_partial<<<nblk, 256, 0, stream>>>(deg, partial, N);
    scan_offsets<<<1, 64, 0, stream>>>(partial, nblk, rowptr, N, E);
    scan_final<<<nblk, 256, 0, stream>>>(deg, partial, rowptr, cursor, dinv, N);
    fill_csr<<<(E + 255) / 256, 256, 0, stream>>>(ei, flag, cursor, colv, E);
    gather_agg<<<(N + 3) / 4, 256, 0, stream>>>(rowptr, colv, x, aggh, N);
    fused_h_hw<<<(N + 31) / 32, 256, 0, stream>>>(aggh, x, WcH, WcL, WgH, WgL, bl, aggh, N);
    gather_gcn_softmax<<<(N + 3) / 4, 256, 0, stream>>>(rowptr, colv, aggh, dinv, bg, out, soft, N);
}